// Round 1
// baseline (1202.436 us; speedup 1.0000x reference)
//
#include <hip/hip_runtime.h>

#define NFC   256
#define DIMD  1024
#define NN    12
#define BTB   64
#define S_TOT 3600
#define BN    768        // BT*N
#define EMB_K 6400       // NFC*5*5
#define IMG_C 768
#define LN_EPS 1e-5f
#define SC    240        // attention s-chunk (16B-aligned stride: 240*4=960B)
#define NCH   15         // chunks per batch (15*240 = 3600)

// ---------------- reduction helpers (block = 256 threads = 4 waves) ----------
__device__ __forceinline__ float waveSum(float v) {
#pragma unroll
  for (int off = 32; off > 0; off >>= 1) v += __shfl_down(v, off, 64);
  return v;
}
__device__ __forceinline__ float blockSum256(float v, float* sm) {
  v = waveSum(v);
  __syncthreads();
  if ((threadIdx.x & 63) == 0) sm[threadIdx.x >> 6] = v;
  __syncthreads();
  return sm[0] + sm[1] + sm[2] + sm[3];
}

// ---------------- K0: all weight transposes [256][Cin] -> [Cin][256] ---------
__global__ __launch_bounds__(256) void k_transpose_all(
    const float* __restrict__ w_ds1, const float* __restrict__ w_emb,
    const float* __restrict__ w_ds2, const float* __restrict__ f1,
    const float* __restrict__ f2,
    float* __restrict__ w1T, float* __restrict__ wembT,
    float* __restrict__ wds2T, float* __restrict__ w1Tf,
    float* __restrict__ w2Tf) {
  int blk = blockIdx.x;
  const float* in; float* out; int Cin; int j;
  if (blk < 1024)      { in = w_ds1; out = w1T;   Cin = 1024; j = blk; }
  else if (blk < 7424) { in = w_emb; out = wembT; Cin = 6400; j = blk - 1024; }
  else if (blk < 8192) { in = w_ds2; out = wds2T; Cin = 768;  j = blk - 7424; }
  else if (blk < 8448) { in = f1;    out = w1Tf;  Cin = 256;  j = blk - 8192; }
  else                 { in = f2;    out = w2Tf;  Cin = 256;  j = blk - 8448; }
  int i = threadIdx.x;
  out[(size_t)j * 256 + i] = in[(size_t)i * Cin + j];
}

// ---------------- K1: ROI downsample1 ----------------------------------------
__global__ __launch_bounds__(256) void k_ds1(const float* __restrict__ RF,   // [BN][1024][25]
                                             const float* __restrict__ w1T,  // [1024][256]
                                             const float* __restrict__ b1,
                                             float* __restrict__ roi_ds) {   // [BN][6400]
  const int r = blockIdx.x;
  const int c = threadIdx.x;
  const float* __restrict__ rf = RF + (size_t)r * (DIMD * 25);
  float acc[25];
#pragma unroll
  for (int p = 0; p < 25; ++p) acc[p] = 0.f;
#pragma unroll 2
  for (int d = 0; d < DIMD; ++d) {
    const float w = w1T[(size_t)d * NFC + c];        // coalesced
#pragma unroll
    for (int p = 0; p < 25; ++p)
      acc[p] = fmaf(w, rf[d * 25 + p], acc[p]);      // uniform -> scalar loads
  }
  const float bias = b1[c];
  float* out = roi_ds + (size_t)r * EMB_K + c * 25;
#pragma unroll
  for (int p = 0; p < 25; ++p) out[p] = acc[p] + bias;
}

// ---------------- K2: emb partial GEMM, k-split 8 ----------------------------
__global__ __launch_bounds__(256) void k_emb_part(const float* __restrict__ roi_ds,
                                                  const float* __restrict__ wembT,
                                                  float* __restrict__ emb_part) { // [8][BN][256]
  const int r0 = blockIdx.x * 16;
  const int kz = blockIdx.y;
  const int c = threadIdx.x;
  const int k0 = kz * (EMB_K / 8);
  float acc[16];
#pragma unroll
  for (int r = 0; r < 16; ++r) acc[r] = 0.f;
#pragma unroll 4
  for (int k = k0; k < k0 + EMB_K / 8; ++k) {
    const float w = wembT[(size_t)k * NFC + c];
#pragma unroll
    for (int r = 0; r < 16; ++r)
      acc[r] = fmaf(w, roi_ds[(size_t)(r0 + r) * EMB_K + k], acc[r]);
  }
#pragma unroll
  for (int r = 0; r < 16; ++r)
    emb_part[((size_t)kz * BN + r0 + r) * NFC + c] = acc[r];
}

__global__ __launch_bounds__(256) void k_emb_reduce(const float* __restrict__ emb_part,
                                                    const float* __restrict__ bemb,
                                                    float* __restrict__ emb) {
  int i = blockIdx.x * 256 + threadIdx.x;
  float s = bemb[i & 255];
#pragma unroll
  for (int z = 0; z < 8; ++z) s += emb_part[(size_t)z * BN * NFC + i];
  emb[i] = s;
}

// ---------------- K3: e2T = (emb @ w_ds2) transposed to [64][768][12] --------
__global__ __launch_bounds__(256) void k_e2(const float* __restrict__ emb,
                                            const float* __restrict__ w_ds2, // [256][768]
                                            float* __restrict__ e2T) {       // [64][768][12]
  const int bn0 = blockIdx.x * 2;            // bn0 even -> both rows same b
  const int b = bn0 / NN;
  const int n0 = bn0 - b * NN;
  const int t = threadIdx.x;
  float a00 = 0, a01 = 0, a02 = 0, a10 = 0, a11 = 0, a12 = 0;
#pragma unroll 4
  for (int o = 0; o < NFC; ++o) {
    const float w0 = w_ds2[(size_t)o * IMG_C + t];
    const float w1 = w_ds2[(size_t)o * IMG_C + t + 256];
    const float w2 = w_ds2[(size_t)o * IMG_C + t + 512];
    const float e0 = emb[(size_t)bn0 * NFC + o];        // uniform
    const float e1 = emb[(size_t)(bn0 + 1) * NFC + o];  // uniform
    a00 = fmaf(e0, w0, a00); a01 = fmaf(e0, w1, a01); a02 = fmaf(e0, w2, a02);
    a10 = fmaf(e1, w0, a10); a11 = fmaf(e1, w1, a11); a12 = fmaf(e1, w2, a12);
  }
  float* __restrict__ dst = e2T + (size_t)b * IMG_C * NN;
  dst[(size_t)t * NN + n0]              = a00;
  dst[(size_t)(t + 256) * NN + n0]      = a01;
  dst[(size_t)(t + 512) * NN + n0]      = a02;
  dst[(size_t)t * NN + n0 + 1]          = a10;
  dst[(size_t)(t + 256) * NN + n0 + 1]  = a11;
  dst[(size_t)(t + 512) * NN + n0 + 1]  = a12;
}

// ---------------- K4: fused flash attention over s-chunks --------------------
// Per (b, chunk): phase A computes scores a[n,s] = e2[b,n,:].F[b,:,s] for the
// chunk (the +emb.b_ds2 bias is constant over s -> cancels in softmax), local
// max m / exp-sum S; phase B accumulates ctx_part[n,c] = sum_s exp(a-m)*F[c,s]
// re-reading the chunk from L2/L3. Combine kernel merges chunks.
// SC=240/NCH=15 -> 960 blocks (~3.75 blk/CU, ~15 waves/CU) for latency hiding;
// s0 is 16B-aligned so phase B uses float4 F-streams + b128 LDS broadcasts.
__global__ __launch_bounds__(256) void k_attn(
    const float* __restrict__ F,    // [64][768][3600]
    const float* __restrict__ e2T,  // [64][768][12]
    float* __restrict__ part,       // [NCH][64][12][768]
    float* __restrict__ pm,         // [64][NCH][12]
    float* __restrict__ ps) {       // [64][NCH][12]
  __shared__ __align__(16) float E_lds[NN][SC];
  __shared__ float redm[4][NN];
  __shared__ float reds[4][NN];
  const int b = blockIdx.y;
  const int ch = blockIdx.x;
  const int t = threadIdx.x;
  const int s0 = ch * SC;
  const float* __restrict__ Fb = F + (size_t)b * IMG_C * S_TOT;
  const float* __restrict__ e2b = e2T + (size_t)b * IMG_C * NN;

  // ---- phase A: scores (one s-slot per lane; lanes >= SC clamped+masked) ----
  const bool act = (t < SC);
  const int sA = s0 + (act ? t : SC - 1);
  float a0[NN];
#pragma unroll
  for (int n = 0; n < NN; ++n) a0[n] = 0.f;
#pragma unroll 4
  for (int c = 0; c < IMG_C; ++c) {
    const float fA = Fb[(size_t)c * S_TOT + sA];
    const float* e2c = e2b + c * NN;                      // uniform, 16B-aligned
    const float4 ea = *reinterpret_cast<const float4*>(e2c);
    const float4 eb = *reinterpret_cast<const float4*>(e2c + 4);
    const float4 ec = *reinterpret_cast<const float4*>(e2c + 8);
    a0[0]  = fmaf(ea.x, fA, a0[0]);
    a0[1]  = fmaf(ea.y, fA, a0[1]);
    a0[2]  = fmaf(ea.z, fA, a0[2]);
    a0[3]  = fmaf(ea.w, fA, a0[3]);
    a0[4]  = fmaf(eb.x, fA, a0[4]);
    a0[5]  = fmaf(eb.y, fA, a0[5]);
    a0[6]  = fmaf(eb.z, fA, a0[6]);
    a0[7]  = fmaf(eb.w, fA, a0[7]);
    a0[8]  = fmaf(ec.x, fA, a0[8]);
    a0[9]  = fmaf(ec.y, fA, a0[9]);
    a0[10] = fmaf(ec.z, fA, a0[10]);
    a0[11] = fmaf(ec.w, fA, a0[11]);
  }

  // ---- batched block max ----
  const int wv = t >> 6, ln = t & 63;
  float m12[NN];
#pragma unroll
  for (int n = 0; n < NN; ++n) {
    float v = act ? a0[n] : -3.0e38f;
#pragma unroll
    for (int off = 32; off > 0; off >>= 1) v = fmaxf(v, __shfl_down(v, off, 64));
    if (ln == 0) redm[wv][n] = v;
  }
  __syncthreads();
#pragma unroll
  for (int n = 0; n < NN; ++n)
    m12[n] = fmaxf(fmaxf(redm[0][n], redm[1][n]), fmaxf(redm[2][n], redm[3][n]));

  // ---- exp, store E to LDS, batched block sum ----
#pragma unroll
  for (int n = 0; n < NN; ++n) {
    const float e0 = act ? expf(a0[n] - m12[n]) : 0.f;
    if (act) E_lds[n][t] = e0;
    float v = e0;
#pragma unroll
    for (int off = 32; off > 0; off >>= 1) v += __shfl_down(v, off, 64);
    if (ln == 0) reds[wv][n] = v;
  }
  __syncthreads();   // covers reds AND E_lds visibility
  float S12[NN];
#pragma unroll
  for (int n = 0; n < NN; ++n)
    S12[n] = reds[0][n] + reds[1][n] + reds[2][n] + reds[3][n];

  if (t == 0) {
#pragma unroll
    for (int n = 0; n < NN; ++n) {
      pm[((size_t)b * NCH + ch) * NN + n] = m12[n];
      ps[((size_t)b * NCH + ch) * NN + n] = S12[n];
    }
  }

  // ---- phase B: ctx partials, lanes own channel c, stream s (L2-hot) ----
  const float4* __restrict__ Ev = reinterpret_cast<const float4*>(&E_lds[0][0]);
#pragma unroll 1
  for (int ci = 0; ci < 3; ++ci) {
    const int c = ci * 256 + t;
    const float4* __restrict__ Fp =
        reinterpret_cast<const float4*>(Fb + (size_t)c * S_TOT + s0);  // 16B-aligned
    float acc[NN];
#pragma unroll
    for (int n = 0; n < NN; ++n) acc[n] = 0.f;
#pragma unroll 2
    for (int q = 0; q < SC / 4; ++q) {      // 60 float4 per lane
      const float4 f = Fp[q];
#pragma unroll
      for (int n = 0; n < NN; ++n) {
        const float4 e = Ev[n * (SC / 4) + q];   // uniform -> b128 broadcast
        acc[n] = fmaf(e.x, f.x, fmaf(e.y, f.y, fmaf(e.z, f.z, fmaf(e.w, f.w, acc[n]))));
      }
    }
#pragma unroll
    for (int n = 0; n < NN; ++n)
      part[(((size_t)ch * BTB + b) * NN + n) * IMG_C + c] = acc[n];
  }
}

// ---------------- K5: combine chunk partials -> ctx768 -----------------------
__global__ __launch_bounds__(256) void k_combine(
    const float* __restrict__ part, const float* __restrict__ pm,
    const float* __restrict__ ps, float* __restrict__ ctx768) {  // [BN][768]
  const int bn = blockIdx.x;            // b*12+n
  const int b = bn / NN, n = bn - b * NN;
  const int t = threadIdx.x;
  float mv[NCH];
  float m = -3.0e38f;
#pragma unroll
  for (int ch = 0; ch < NCH; ++ch) {
    mv[ch] = pm[((size_t)b * NCH + ch) * NN + n];
    m = fmaxf(m, mv[ch]);
  }
  float Z = 0.f, al[NCH];
#pragma unroll
  for (int ch = 0; ch < NCH; ++ch) {
    al[ch] = expf(mv[ch] - m);
    Z += ps[((size_t)b * NCH + ch) * NN + n] * al[ch];
  }
  const float rz = 1.0f / Z;
#pragma unroll 1
  for (int ci = 0; ci < 3; ++ci) {
    const int c = ci * 256 + t;
    float s = 0.f;
#pragma unroll
    for (int ch = 0; ch < NCH; ++ch)
      s += part[(((size_t)ch * BTB + b) * NN + n) * IMG_C + c] * al[ch];
    ctx768[(size_t)bn * IMG_C + c] = s * rz;
  }
}

// ---------------- K6: ctx = W_ds2 . ctx768 + b_ds2, +emb residual, LN1 -------
__global__ __launch_bounds__(256) void k_ctx_ln1(
    const float* __restrict__ ctx768, const float* __restrict__ wds2T, // [768][256]
    const float* __restrict__ b_ds2, const float* __restrict__ emb,
    const float* __restrict__ g, const float* __restrict__ be,
    float* __restrict__ x) {
  __shared__ float sm[4];
  const int r0 = blockIdx.x * 4;
  const int o = threadIdx.x;
  float acc[4] = {0.f, 0.f, 0.f, 0.f};
#pragma unroll 2
  for (int cc = 0; cc < IMG_C; ++cc) {
    const float w = wds2T[(size_t)cc * NFC + o];
#pragma unroll
    for (int r = 0; r < 4; ++r)
      acc[r] = fmaf(w, ctx768[(size_t)(r0 + r) * IMG_C + cc], acc[r]);  // uniform
  }
  const float bv = b_ds2[o], gv = g[o], bev = be[o];
#pragma unroll 1
  for (int r = 0; r < 4; ++r) {
    const float val = acc[r] + bv + emb[(size_t)(r0 + r) * NFC + o];
    const float mu = blockSum256(val, sm) * (1.0f / NFC);
    const float d = val - mu;
    const float var = blockSum256(d * d, sm) * (1.0f / NFC);
    x[(size_t)(r0 + r) * NFC + o] = d * rsqrtf(var + LN_EPS) * gv + bev;
  }
}

// ---------------- K7: FFN + residual + LN2 -----------------------------------
__global__ __launch_bounds__(256) void k_ffn_ln2(const float* __restrict__ x,
                                                 const float* __restrict__ w1T,
                                                 const float* __restrict__ b1,
                                                 const float* __restrict__ w2T,
                                                 const float* __restrict__ b2,
                                                 const float* __restrict__ g2,
                                                 const float* __restrict__ be2,
                                                 float* __restrict__ out) {
  __shared__ float hs[8][NFC];
  __shared__ float sm[4];
  const int r0 = blockIdx.x * 8;
  const int o = threadIdx.x;
  float acc[8];
#pragma unroll
  for (int r = 0; r < 8; ++r) acc[r] = 0.f;
#pragma unroll 4
  for (int c = 0; c < NFC; ++c) {
    const float w = w1T[(size_t)c * NFC + o];
#pragma unroll
    for (int r = 0; r < 8; ++r)
      acc[r] = fmaf(w, x[(size_t)(r0 + r) * NFC + c], acc[r]);
  }
  const float bb = b1[o];
#pragma unroll
  for (int r = 0; r < 8; ++r) hs[r][o] = fmaxf(acc[r] + bb, 0.0f);
  __syncthreads();
  float acc2[8];
#pragma unroll
  for (int r = 0; r < 8; ++r) acc2[r] = 0.f;
#pragma unroll 4
  for (int c = 0; c < NFC; ++c) {
    const float w = w2T[(size_t)c * NFC + o];
#pragma unroll
    for (int r = 0; r < 8; ++r) acc2[r] = fmaf(w, hs[r][c], acc2[r]);
  }
  const float b2v = b2[o], gv = g2[o], bev = be2[o];
#pragma unroll 1
  for (int r = 0; r < 8; ++r) {
    const float val = acc2[r] + b2v + x[(size_t)(r0 + r) * NFC + o];
    const float mu = blockSum256(val, sm) * (1.0f / NFC);
    const float d = val - mu;
    const float var = blockSum256(d * d, sm) * (1.0f / NFC);
    out[(size_t)(r0 + r) * NFC + o] = d * rsqrtf(var + LN_EPS) * gv + bev;
  }
}

// ---------------- launch -----------------------------------------------------
extern "C" void kernel_launch(void* const* d_in, const int* in_sizes, int n_in,
                              void* d_out, int out_size, void* d_ws, size_t ws_size,
                              hipStream_t stream) {
  const float* roi_feature   = (const float*)d_in[0];
  const float* image_feature = (const float*)d_in[1];
  const float* w_ds1  = (const float*)d_in[2];
  const float* b_ds1  = (const float*)d_in[3];
  const float* w_ds2  = (const float*)d_in[4];
  const float* b_ds2  = (const float*)d_in[5];
  const float* w_emb  = (const float*)d_in[6];
  const float* b_emb  = (const float*)d_in[7];
  const float* g1     = (const float*)d_in[8];
  const float* be1    = (const float*)d_in[9];
  const float* ffn_w1 = (const float*)d_in[10];
  const float* ffn_b1 = (const float*)d_in[11];
  const float* ffn_w2 = (const float*)d_in[12];
  const float* ffn_b2 = (const float*)d_in[13];
  const float* g2     = (const float*)d_in[14];
  const float* be2    = (const float*)d_in[15];
  float* out = (float*)d_out;

  float* p = (float*)d_ws;
  float* w1T    = p;   p += 1024 * 256;
  float* wembT  = p;   p += 6400 * 256;
  float* wds2T  = p;   p += 768 * 256;
  float* w1Tf   = p;   p += 256 * 256;
  float* w2Tf   = p;   p += 256 * 256;
  float* roi_ds = p;   p += 768 * 6400;
  float* emb_part = p; p += 8 * 768 * 256;
  float* emb    = p;   p += 768 * 256;
  float* e2T    = p;   p += 768 * 768;                   // [64][768][12]
  float* part   = p;   p += (size_t)NCH * BTB * NN * IMG_C;  // 8.85M floats
  float* pm     = p;   p += BTB * NCH * NN;
  float* ps     = p;   p += BTB * NCH * NN;
  float* ctx768 = p;   p += 768 * 768;
  float* xb     = p;   p += 768 * 256;

  k_transpose_all<<<8704, 256, 0, stream>>>(w_ds1, w_emb, w_ds2, ffn_w1, ffn_w2,
                                            w1T, wembT, wds2T, w1Tf, w2Tf);
  k_ds1<<<BN, 256, 0, stream>>>(roi_feature, w1T, b_ds1, roi_ds);
  k_emb_part<<<dim3(48, 8), 256, 0, stream>>>(roi_ds, wembT, emb_part);
  k_emb_reduce<<<768, 256, 0, stream>>>(emb_part, b_emb, emb);
  k_e2<<<384, 256, 0, stream>>>(emb, w_ds2, e2T);
  k_attn<<<dim3(NCH, BTB), 256, 0, stream>>>(image_feature, e2T, part, pm, ps);
  k_combine<<<768, 256, 0, stream>>>(part, pm, ps, ctx768);
  k_ctx_ln1<<<192, 256, 0, stream>>>(ctx768, wds2T, b_ds2, emb, g1, be1, xb);
  k_ffn_ln2<<<96, 256, 0, stream>>>(xb, w1Tf, ffn_b1, w2Tf, ffn_b2, g2, be2, out);
}